// Round 14
// baseline (109.587 us; speedup 1.0000x reference)
//
#include <hip/hip_runtime.h>
#include <hip/hip_bf16.h>

typedef __attribute__((ext_vector_type(4))) float f32x4;
typedef __bf16 bf16x8 __attribute__((ext_vector_type(8)));
using bf16 = __hip_bfloat16;

typedef __attribute__((address_space(1))) const void* gptr_t;
typedef __attribute__((address_space(3))) void* lptr_t;
typedef __attribute__((address_space(3))) char* lchar_t;

// Problem constants
constexpr int BB = 2, SS = 2048, DDIM = 512, NHEAD = 8, HDIM = 64, MLPD = 2048;
constexpr int NTOK = BB * SS;          // 4096
constexpr int WHALF = 256;             // window // 2
constexpr int NGLOB = 64;
constexpr float NEGBIG = -1e10f;

// Workspace layout (bytes)
constexpr size_t SZ_X1    = (size_t)NTOK * DDIM * 2;
constexpr size_t SZ_WQKVT = (size_t)1536 * DDIM * 2;
constexpr size_t SZ_WOT   = (size_t)DDIM * DDIM * 2;
constexpr size_t SZ_W1T   = (size_t)MLPD * DDIM * 2;
constexpr size_t SZ_W2T   = (size_t)DDIM * MLPD * 2;
constexpr size_t SZ_HEAD  = (size_t)BB * NHEAD * SS * HDIM * 2;
constexpr size_t SZ_QKV   = 3 * SZ_HEAD;
constexpr size_t SZ_CTX   = (size_t)NTOK * DDIM * 2;
constexpr size_t SZ_XRES  = (size_t)NTOK * DDIM * 4;
constexpr size_t SZ_Y1    = (size_t)NTOK * DDIM * 2;
constexpr size_t SZ_H1    = (size_t)NTOK * MLPD * 2;

constexpr size_t OFF_X1    = 0;
constexpr size_t OFF_WQKVT = OFF_X1 + SZ_X1;
constexpr size_t OFF_WOT   = OFF_WQKVT + SZ_WQKVT;
constexpr size_t OFF_W1T   = OFF_WOT + SZ_WOT;
constexpr size_t OFF_W2T   = OFF_W1T + SZ_W1T;
constexpr size_t OFF_QKV   = OFF_W2T + SZ_W2T;
constexpr size_t OFF_CTX   = OFF_QKV + SZ_QKV;
constexpr size_t OFF_XRES  = OFF_CTX + SZ_CTX;
constexpr size_t OFF_Y1    = OFF_XRES + SZ_XRES;
constexpr size_t OFF_H1    = OFF_Y1 + SZ_Y1;
constexpr size_t OFF_GACC  = OFF_H1 + SZ_H1;                        // [64][64][64] f32
constexpr size_t OFF_GL    = OFF_GACC + (size_t)64 * 64 * 64 * 4;   // [64][64] f32

// ---------------------------------------------------------------------------
// Prep kernel: blocks 0..767 = weight transpose+cast; 768..1791 = LN1.
// ---------------------------------------------------------------------------
struct TcEnt { const float* src; bf16* dst; int K, N, tiles_x, start; float scale; };
struct PrepArgs {
  TcEnt e[6];
  const float* x; const float* ln_s; const float* ln_b; bf16* ln_out;
};

__global__ void prep_kernel(PrepArgs a) {
  __shared__ __align__(16) bf16 tile[64][65];
  int bid = blockIdx.x;
  int t = threadIdx.x;
  if (bid < 768) {
    int wi = 5;
#pragma unroll
    for (int i = 4; i >= 0; --i)
      if (bid < a.e[i + 1].start) wi = i;
    const TcEnt& E = a.e[wi];
    int local = bid - E.start;
    int bx = local % E.tiles_x, by = local / E.tiles_x;
    int k0 = by * 64, n0 = bx * 64;
    for (int it = 0; it < 16; ++it) {
      int idx = it * 256 + t;
      int r = idx >> 6, c = idx & 63;
      float v = E.src[(size_t)(k0 + r) * E.N + n0 + c] * E.scale;
      tile[c][r] = __float2bfloat16(v);
    }
    __syncthreads();
    for (int it = 0; it < 16; ++it) {
      int idx = it * 256 + t;
      int r = idx >> 6, c = idx & 63;
      E.dst[(size_t)(n0 + r) * E.K + k0 + c] = tile[r][c];
    }
  } else {
    int wv = t >> 6;
    int lane = t & 63;
    int row = (bid - 768) * 4 + wv;
    const float* xr = a.x + (size_t)row * DDIM + lane * 8;
    float4 v0 = *(const float4*)(xr);
    float4 v1 = *(const float4*)(xr + 4);
    float vv[8] = {v0.x, v0.y, v0.z, v0.w, v1.x, v1.y, v1.z, v1.w};
    float s = 0.f;
    for (int i = 0; i < 8; ++i) s += vv[i];
    for (int m = 1; m < 64; m <<= 1) s += __shfl_xor(s, m, 64);
    float mean = s * (1.0f / DDIM);
    float vs = 0.f;
    for (int i = 0; i < 8; ++i) { float d = vv[i] - mean; vs += d * d; }
    for (int m = 1; m < 64; m <<= 1) vs += __shfl_xor(vs, m, 64);
    float rstd = rsqrtf(vs * (1.0f / DDIM) + 1e-6f);
    __align__(16) bf16 ov[8];
    int c0 = lane * 8;
    for (int i = 0; i < 8; ++i) {
      float y = (vv[i] - mean) * rstd * a.ln_s[c0 + i] + a.ln_b[c0 + i];
      ov[i] = __float2bfloat16(y);
    }
    *(uint4*)(&a.ln_out[(size_t)row * DDIM + c0]) = *(const uint4*)ov;
  }
}

// ---------------------------------------------------------------------------
// LayerNorm (fp32 in) -> bf16 out. One wave per 512-el row.
// ---------------------------------------------------------------------------
__global__ void ln_kernel(const float* __restrict__ x, const float* __restrict__ sc,
                          const float* __restrict__ bi, bf16* __restrict__ out) {
  int wv = threadIdx.x >> 6;
  int lane = threadIdx.x & 63;
  int row = blockIdx.x * 4 + wv;
  const float* xr = x + (size_t)row * DDIM + lane * 8;
  float4 v0 = *(const float4*)(xr);
  float4 v1 = *(const float4*)(xr + 4);
  float vv[8] = {v0.x, v0.y, v0.z, v0.w, v1.x, v1.y, v1.z, v1.w};
  float s = 0.f;
  for (int i = 0; i < 8; ++i) s += vv[i];
  for (int m = 1; m < 64; m <<= 1) s += __shfl_xor(s, m, 64);
  float mean = s * (1.0f / DDIM);
  float vs = 0.f;
  for (int i = 0; i < 8; ++i) { float d = vv[i] - mean; vs += d * d; }
  for (int m = 1; m < 64; m <<= 1) vs += __shfl_xor(vs, m, 64);
  float rstd = rsqrtf(vs * (1.0f / DDIM) + 1e-6f);
  __align__(16) bf16 ov[8];
  int c0 = lane * 8;
  for (int i = 0; i < 8; ++i) {
    float y = (vv[i] - mean) * rstd * sc[c0 + i] + bi[c0 + i];
    ov[i] = __float2bfloat16(y);
  }
  *(uint4*)(&out[(size_t)row * DDIM + c0]) = *(const uint4*)ov;
}

// ---------------------------------------------------------------------------
// GEMM: LDS staging via global_load_lds. DEPTH=2: classic 2-phase (stage t+1,
// vmcnt(0), barrier). DEPTH=3: counted-vmcnt deep pipeline (stage t+2 before
// compute(t); vmcnt(LOADS) leaves stage(t+1) landed; ~2 epochs landing window).
// NP = K-panels per epoch (epoch K-step = NP*64).
// ---------------------------------------------------------------------------
template <int BM, int BN, int NP, int DEPTH, int EPI>
__global__ __launch_bounds__(256,
    ((DEPTH * NP * (BM + BN) * 128 / 1024) <= 32) ? 4 :
    (((DEPTH * NP * (BM + BN) * 128 / 1024) <= 48) ? 3 : 2))
void gemm_kernel(const bf16* __restrict__ A, const bf16* __restrict__ BT,
                 int M, int N, int K, int gx,
                 const float* __restrict__ ep_add, const float* __restrict__ ep_bias,
                 void* __restrict__ out0) {
  constexpr int AM = BM / 32;
  constexpr int AN = BN / 32;
  constexpr int CA4 = (BM / 8) / 4;
  constexpr int CB4 = (BN / 8) / 4;
  constexpr int LOADS = NP * (CA4 + CB4);   // per-wave global_load_lds per stage
  __shared__ __align__(16) bf16 As[DEPTH][NP][BM][64];
  __shared__ __align__(16) bf16 Bs[DEPTH][NP][BN][64];
  int t = threadIdx.x;
  int wv = t >> 6, lane = t & 63;
  int wr = wv >> 1, wc = wv & 1;
  int g = lane >> 4, lr = lane & 15;
  int sub_r = lane >> 3, sub_s = lane & 7;
  int nwg = gridDim.x;
  int bid = blockIdx.x;
  int swz = (bid & 7) * (nwg >> 3) + (bid >> 3);
  int m0 = (swz / gx) * BM;
  int n0 = (swz % gx) * BN;
  lchar_t asA = (lchar_t)&As[0][0][0][0];
  lchar_t asB = (lchar_t)&Bs[0][0][0][0];

  auto stage = [&](int kt, int bb) {
    int k0 = kt * (64 * NP);
#pragma unroll
    for (int p = 0; p < NP; ++p) {
#pragma unroll
      for (int i = 0; i < CA4; ++i) {
        int c = wv + 4 * i;
        int row = c * 8 + sub_r;
        int cb = sub_s ^ sub_r;
        __builtin_amdgcn_global_load_lds(
            (gptr_t)&A[(size_t)(m0 + row) * K + k0 + p * 64 + cb * 8],
            (lptr_t)(asA + bb * (NP * BM * 128) + p * (BM * 128) + c * 1024), 16, 0, 0);
      }
#pragma unroll
      for (int i = 0; i < CB4; ++i) {
        int c = wv + 4 * i;
        int row = c * 8 + sub_r;
        int cb = sub_s ^ sub_r;
        __builtin_amdgcn_global_load_lds(
            (gptr_t)&BT[(size_t)(n0 + row) * K + k0 + p * 64 + cb * 8],
            (lptr_t)(asB + bb * (NP * BN * 128) + p * (BN * 128) + c * 1024), 16, 0, 0);
      }
    }
  };

  f32x4 acc[AM][AN] = {};
  int NT = K / (64 * NP);

  if constexpr (DEPTH == 2) {
    stage(0, 0);
    asm volatile("s_waitcnt vmcnt(0)" ::: "memory");
  } else {
    stage(0, 0);
    if (NT > 1) {
      stage(1, 1);
      asm volatile("s_waitcnt vmcnt(%0)" :: "i"(LOADS) : "memory");
    } else {
      asm volatile("s_waitcnt vmcnt(0)" ::: "memory");
    }
  }
  __builtin_amdgcn_s_barrier();
  __builtin_amdgcn_sched_barrier(0);

  for (int kt = 0; kt < NT; ++kt) {
    int bb;
    if constexpr (DEPTH == 2) {
      bb = kt & 1;
      if (kt + 1 < NT) stage(kt + 1, bb ^ 1);
    } else {
      bb = kt % 3;
      int nn = kt + 2;
      if (nn < NT) stage(nn, nn % 3);
    }
    const char* Ab = (const char*)&As[0][0][0][0] + bb * (NP * BM * 128);
    const char* Bb = (const char*)&Bs[0][0][0][0] + bb * (NP * BN * 128);
#pragma unroll
    for (int p = 0; p < NP; ++p) {
#pragma unroll
      for (int h = 0; h < 2; ++h) {
        bf16x8 af[AM], bfr[AN];
#pragma unroll
        for (int i = 0; i < AM; ++i) {
          int row = wr * (BM / 2) + i * 16 + lr;
          int sl = (h * 4 + g) ^ (row & 7);
          af[i] = *(const bf16x8*)(Ab + p * (BM * 128) + row * 128 + sl * 16);
        }
#pragma unroll
        for (int j = 0; j < AN; ++j) {
          int row = wc * (BN / 2) + j * 16 + lr;
          int sl = (h * 4 + g) ^ (row & 7);
          bfr[j] = *(const bf16x8*)(Bb + p * (BN * 128) + row * 128 + sl * 16);
        }
#pragma unroll
        for (int i = 0; i < AM; ++i)
#pragma unroll
          for (int j = 0; j < AN; ++j)
            acc[i][j] = __builtin_amdgcn_mfma_f32_16x16x32_bf16(af[i], bfr[j], acc[i][j], 0, 0, 0);
      }
    }
    if constexpr (DEPTH == 2) {
      asm volatile("s_waitcnt vmcnt(0)" ::: "memory");
    } else {
      if (kt + 2 < NT)
        asm volatile("s_waitcnt vmcnt(%0)" :: "i"(LOADS) : "memory");
      else
        asm volatile("s_waitcnt vmcnt(0)" ::: "memory");
    }
    __builtin_amdgcn_s_barrier();
    __builtin_amdgcn_sched_barrier(0);
  }
#pragma unroll
  for (int i = 0; i < AM; ++i)
#pragma unroll
    for (int j = 0; j < AN; ++j)
#pragma unroll
      for (int r = 0; r < 4; ++r) {
        int m = m0 + wr * (BM / 2) + i * 16 + g * 4 + r;
        int n = n0 + wc * (BN / 2) + j * 16 + lr;
        float val = acc[i][j][r];
        if constexpr (EPI == 0) {
          bf16* qkv = (bf16*)out0;
          int which = n >> 9;
          int hh = (n >> 6) & 7;
          int hd = n & 63;
          int b = m >> 11, sTok = m & 2047;
          size_t off;
          if (which == 2) {
            off = (size_t)2 * (BB * NHEAD * SS * HDIM) +
                  ((size_t)(b * NHEAD + hh) * HDIM + hd) * SS + sTok;
          } else {
            off = (size_t)which * (BB * NHEAD * SS * HDIM) +
                  ((size_t)(b * NHEAD + hh) * SS + sTok) * HDIM + hd;
          }
          qkv[off] = __float2bfloat16(val);
        } else if constexpr (EPI == 1) {
          ((float*)out0)[(size_t)m * N + n] = val + ep_add[(size_t)m * N + n];
        } else if constexpr (EPI == 2) {
          float xb = val + ep_bias[n];
          float u = 1.5957691216057308f * (xb + 0.044715f * xb * xb * xb);
          float ge = xb / (1.0f + __expf(-u));
          ((bf16*)out0)[(size_t)m * N + n] = __float2bfloat16(ge);
        } else {
          ((float*)out0)[(size_t)m * N + n] = val + ep_bias[n] + ep_add[(size_t)m * N + n];
        }
      }
}

// ---------------------------------------------------------------------------
// Block-sparse flash attention v8c: v8b + s_setprio(1) around MFMA clusters.
// ---------------------------------------------------------------------------
constexpr int NBANDQ = (SS - NGLOB) / 64;      // 31 band q-tiles per head
constexpr int NBAND8 = 16 * NBANDQ;            // 496
constexpr int NGSPL8 = 16 * 4;                 // 64 (1 q-tile x 4 kv-splits)
constexpr int NWG8   = NBAND8 + NGSPL8;        // 560 (divisible by 8)

__global__ __launch_bounds__(256, 3)
void attn_kernel(const bf16* __restrict__ Qb, const bf16* __restrict__ Kb,
                 const bf16* __restrict__ VTb, bf16* __restrict__ ctx,
                 float* __restrict__ gacc, float* __restrict__ gl) {
  __shared__ __align__(16) bf16 Ks[2][64][64];   // [buf][key][d]   8KB each
  __shared__ __align__(16) bf16 Vs[2][64][64];   // [buf][d][key]   8KB each
  __shared__ __align__(16) bf16 Plds[4][16][72];
  int t = threadIdx.x;
  int w = t >> 6, lane = t & 63;
  int g = lane >> 4, lr = lane & 15;
  int sub_r = lane >> 3, sub_s = lane & 7;
  int bid = blockIdx.x;
  int swz = (bid & 7) * (NWG8 / 8) + (bid >> 3);

  bool isBand = swz < NBAND8;
  int bh, qq0, k0 = 0, sp = 0;
  if (isBand) {
    bh = swz / NBANDQ;
    qq0 = NGLOB + (swz % NBANDQ) * 64;           // 64..1984
  } else {
    int gidx = swz - NBAND8;
    bh = gidx >> 2;
    sp = gidx & 3;
    qq0 = 0;                                     // global rows 0..63
    k0 = sp * (SS / 4);
  }
  int b = bh >> 3, h = bh & 7;
  const bf16* Qh = Qb + (size_t)bh * SS * HDIM;
  const bf16* Kh = Kb + (size_t)bh * SS * HDIM;
  const bf16* VTh = VTb + (size_t)bh * HDIM * SS;
  int qq0w = qq0 + w * 16;

  bf16x8 aq0 = *(const bf16x8*)&Qh[(size_t)(qq0w + lr) * HDIM + g * 8];
  bf16x8 aq1 = *(const bf16x8*)&Qh[(size_t)(qq0w + lr) * HDIM + 32 + g * 8];

  lchar_t ksB = (lchar_t)&Ks[0][0][0];
  lchar_t vsB = (lchar_t)&Vs[0][0][0];
  int cb = sub_s ^ sub_r;

  auto stageKV = [&](int kb, int bb) {
#pragma unroll
    for (int i = 0; i < 2; ++i) {
      int c = w + 4 * i;
      int row = c * 8 + sub_r;
      __builtin_amdgcn_global_load_lds(
          (gptr_t)&Kh[(size_t)(kb + row) * HDIM + cb * 8],
          (lptr_t)(ksB + bb * 8192 + c * 1024), 16, 0, 0);
      __builtin_amdgcn_global_load_lds(
          (gptr_t)&VTh[(size_t)row * SS + kb + cb * 8],
          (lptr_t)(vsB + bb * 8192 + c * 1024), 16, 0, 0);
    }
  };

  float lsum[4] = {0.f, 0.f, 0.f, 0.f};
  f32x4 accO[4] = {};
  const char* ksR = (const char*)&Ks[0][0][0];
  const char* vsR = (const char*)&Vs[0][0][0];

  auto computeT = [&](int kb, int bb, bool domask) {
    const char* Kb_ = ksR + bb * 8192;
    const char* Vb_ = vsR + bb * 8192;
    f32x4 s[4];
    __builtin_amdgcn_s_setprio(1);
#pragma unroll
    for (int sub = 0; sub < 4; ++sub) {
      int row = sub * 16 + lr;
      int sl0 = g ^ (row & 7);
      int sl1 = (4 + g) ^ (row & 7);
      bf16x8 ka = *(const bf16x8*)(Kb_ + row * 128 + sl0 * 16);
      bf16x8 kc = *(const bf16x8*)(Kb_ + row * 128 + sl1 * 16);
      f32x4 z = {};
      z = __builtin_amdgcn_mfma_f32_16x16x32_bf16(aq0, ka, z, 0, 0, 0);
      z = __builtin_amdgcn_mfma_f32_16x16x32_bf16(aq1, kc, z, 0, 0, 0);
      s[sub] = z;
    }
    __builtin_amdgcn_s_setprio(0);
    if (domask) {
#pragma unroll
      for (int sub = 0; sub < 4; ++sub)
#pragma unroll
        for (int r = 0; r < 4; ++r) {
          int i = qq0w + g * 4 + r;
          int d = i - (kb + sub * 16 + lr);
          bool ok = (unsigned)(d + WHALF) <= 2u * WHALF;
          s[sub][r] = ok ? s[sub][r] : NEGBIG;
        }
    }
    float p[4][4];
#pragma unroll
    for (int sub = 0; sub < 4; ++sub)
#pragma unroll
      for (int r = 0; r < 4; ++r) p[sub][r] = __expf(s[sub][r]);
#pragma unroll
    for (int r = 0; r < 4; ++r)
      lsum[r] += (p[0][r] + p[1][r]) + (p[2][r] + p[3][r]);
#pragma unroll
    for (int sub = 0; sub < 4; ++sub)
#pragma unroll
      for (int r = 0; r < 4; ++r)
        Plds[w][g * 4 + r][sub * 16 + lr] = __float2bfloat16(p[sub][r]);
    asm volatile("s_waitcnt lgkmcnt(0)" ::: "memory");
    __builtin_amdgcn_sched_barrier(0);
    bf16x8 paLo = *(const bf16x8*)&Plds[w][lr][g * 8];
    bf16x8 paHi = *(const bf16x8*)&Plds[w][lr][32 + g * 8];
    __builtin_amdgcn_s_setprio(1);
#pragma unroll
    for (int dc = 0; dc < 4; ++dc) {
      int row = dc * 16 + lr;
      int slLo = g ^ (row & 7);
      int slHi = (4 + g) ^ (row & 7);
      bf16x8 vfLo = *(const bf16x8*)(Vb_ + row * 128 + slLo * 16);
      bf16x8 vfHi = *(const bf16x8*)(Vb_ + row * 128 + slHi * 16);
      accO[dc] = __builtin_amdgcn_mfma_f32_16x16x32_bf16(paLo, vfLo, accO[dc], 0, 0, 0);
      accO[dc] = __builtin_amdgcn_mfma_f32_16x16x32_bf16(paHi, vfHi, accO[dc], 0, 0, 0);
    }
    __builtin_amdgcn_s_setprio(0);
  };

  int bs = 0, nt;
  if (isBand) {
    int blo = qq0 - WHALF;
    bs = (blo < NGLOB) ? NGLOB : (blo & ~63);
    int be = qq0 + 64 + WHALF;
    if (be > SS) be = SS;
    nt = 1 + ((be - bs + 63) >> 6);
  } else {
    nt = (SS / 4) / 64;                          // 8
  }
  auto kb_of = [&](int i) {
    if (isBand) return (i == 0) ? 0 : bs + (i - 1) * 64;
    return k0 + i * 64;
  };

  stageKV(kb_of(0), 0);
  asm volatile("s_waitcnt vmcnt(0)" ::: "memory");
  __builtin_amdgcn_s_barrier();
  __builtin_amdgcn_sched_barrier(0);
  for (int i = 0; i < nt; ++i) {
    int bb = i & 1;
    if (i + 1 < nt) stageKV(kb_of(i + 1), bb ^ 1);
    int kb = kb_of(i);
    bool domask = isBand && (i > 0) &&
                  ((kb < qq0w - 241) || (kb + 63 > qq0w + WHALF));
    computeT(kb, bb, domask);
    asm volatile("s_waitcnt vmcnt(0)" ::: "memory");
    __builtin_amdgcn_s_barrier();
    __builtin_amdgcn_sched_barrier(0);
  }

#pragma unroll
  for (int m = 1; m < 16; m <<= 1)
#pragma unroll
    for (int r = 0; r < 4; ++r) lsum[r] += __shfl_xor(lsum[r], m, 64);

  if (isBand) {
#pragma unroll
    for (int r = 0; r < 4; ++r) {
      float rL = 1.0f / lsum[r];
      int m = b * SS + qq0w + g * 4 + r;
#pragma unroll
      for (int dc = 0; dc < 4; ++dc) {
        int col = h * HDIM + dc * 16 + lr;
        ctx[(size_t)m * DDIM + col] = __float2bfloat16(accO[dc][r] * rL);
      }
    }
  } else {
    int grp = bh * 4 + sp;
#pragma unroll
    for (int r = 0; r < 4; ++r) {
      int rowi = w * 16 + g * 4 + r;
#pragma unroll
      for (int dc = 0; dc < 4; ++dc)
        gacc[((size_t)grp * 64 + rowi) * 64 + dc * 16 + lr] = accO[dc][r];
      if (lr == 0) gl[grp * 64 + rowi] = lsum[r];
    }
  }
}

// Merge the 4 KV-splits of each head's global q-rows (plain sums, shared m==0).
__global__ __launch_bounds__(64, 4)
void attn_combine_kernel(const float* __restrict__ gacc, const float* __restrict__ gl,
                         bf16* __restrict__ ctx) {
  int bh = blockIdx.x;            // 0..15
  int b = bh >> 3, h = bh & 7;
  int c = threadIdx.x;
  for (int r = 0; r < 64; ++r) {
    float L = 0.f, val = 0.f;
    for (int s2 = 0; s2 < 4; ++s2) {
      L += gl[(bh * 4 + s2) * 64 + r];
      val += gacc[((size_t)(bh * 4 + s2) * 64 + r) * 64 + c];
    }
    ctx[(size_t)(b * SS + r) * DDIM + h * HDIM + c] = __float2bfloat16(val / L);
  }
}

// ---------------------------------------------------------------------------
extern "C" void kernel_launch(void* const* d_in, const int* in_sizes, int n_in,
                              void* d_out, int out_size, void* d_ws, size_t ws_size,
                              hipStream_t stream) {
  const float* inputs = (const float*)d_in[0];
  const float* ln1_s = (const float*)d_in[2];
  const float* ln1_b = (const float*)d_in[3];
  const float* wq = (const float*)d_in[4];
  const float* wk = (const float*)d_in[5];
  const float* wv = (const float*)d_in[6];
  const float* wo = (const float*)d_in[7];
  const float* ln2_s = (const float*)d_in[8];
  const float* ln2_b = (const float*)d_in[9];
  const float* w1 = (const float*)d_in[10];
  const float* b1 = (const float*)d_in[11];
  const float* w2 = (const float*)d_in[12];
  const float* b2 = (const float*)d_in[13];

  char* ws = (char*)d_ws;
  bf16* x1    = (bf16*)(ws + OFF_X1);
  bf16* wqkvT = (bf16*)(ws + OFF_WQKVT);
  bf16* woT   = (bf16*)(ws + OFF_WOT);
  bf16* w1T   = (bf16*)(ws + OFF_W1T);
  bf16* w2T   = (bf16*)(ws + OFF_W2T);
  bf16* qkv   = (bf16*)(ws + OFF_QKV);
  bf16* ctx   = (bf16*)(ws + OFF_CTX);
  float* xres = (float*)(ws + OFF_XRES);
  bf16* y1    = (bf16*)(ws + OFF_Y1);
  bf16* h1    = (bf16*)(ws + OFF_H1);
  float* gacc = (float*)(ws + OFF_GACC);
  float* gl   = (float*)(ws + OFF_GL);
  size_t headsz = (size_t)BB * NHEAD * SS * HDIM;

  // Prep: 6 weight transposes (fold 1/8 into wq) + LN1 in one launch
  PrepArgs pa;
  pa.e[0] = {wq, wqkvT,                       512, 512,  8,   0, 0.125f};
  pa.e[1] = {wk, wqkvT + (size_t)512 * 512,   512, 512,  8,  64, 1.f};
  pa.e[2] = {wv, wqkvT + (size_t)1024 * 512,  512, 512,  8, 128, 1.f};
  pa.e[3] = {wo, woT,                         512, 512,  8, 192, 1.f};
  pa.e[4] = {w1, w1T,                         512, 2048, 32, 256, 1.f};
  pa.e[5] = {w2, w2T,                         2048, 512, 8, 512, 1.f};
  pa.x = inputs; pa.ln_s = ln1_s; pa.ln_b = ln1_b; pa.ln_out = x1;
  prep_kernel<<<768 + NTOK / 4, 256, 0, stream>>>(pa);

  // QKV projection (V written transposed): 64x128, BK=64, DEPTH=2, 3/CU
  gemm_kernel<64, 128, 1, 2, 0><<<12 * 64, 256, 0, stream>>>(x1, wqkvT, NTOK, 1536, 512, 12, nullptr, nullptr, qkv);
  // Attention: 64-row q-tiles, 4 waves, 560 blocks, 3/CU, setprio on MFMA
  attn_kernel<<<NWG8, 256, 0, stream>>>(qkv, qkv + headsz, qkv + 2 * headsz, ctx, gacc, gl);
  attn_combine_kernel<<<16, 64, 0, stream>>>(gacc, gl, ctx);
  // Output projection + residual: 64x64, BK=64, DEPTH=3 counted-vmcnt, 3/CU
  gemm_kernel<64, 64, 1, 3, 1><<<8 * 64, 256, 0, stream>>>(ctx, woT, NTOK, 512, 512, 8, inputs, nullptr, xres);
  // LN2
  ln_kernel<<<NTOK / 4, 256, 0, stream>>>(xres, ln2_s, ln2_b, y1);
  // MLP up: 128x128, BK=64, DEPTH=2, 2/CU exact
  gemm_kernel<128, 128, 1, 2, 2><<<16 * 32, 256, 0, stream>>>(y1, w1T, NTOK, 2048, 512, 16, nullptr, b1, h1);
  // MLP down: 64x64, BK=64, DEPTH=3 counted-vmcnt, 3/CU
  gemm_kernel<64, 64, 1, 3, 3><<<8 * 64, 256, 0, stream>>>(h1, w2T, NTOK, 512, 2048, 8, xres, b2, (float*)d_out);
}

// Round 15
// 95.208 us; speedup vs baseline: 1.1510x; 1.1510x over previous
//
#include <hip/hip_runtime.h>
#include <hip/hip_bf16.h>

typedef __attribute__((ext_vector_type(4))) float f32x4;
typedef __bf16 bf16x8 __attribute__((ext_vector_type(8)));
using bf16 = __hip_bfloat16;

typedef __attribute__((address_space(1))) const void* gptr_t;
typedef __attribute__((address_space(3))) void* lptr_t;
typedef __attribute__((address_space(3))) char* lchar_t;

// Problem constants
constexpr int BB = 2, SS = 2048, DDIM = 512, NHEAD = 8, HDIM = 64, MLPD = 2048;
constexpr int NTOK = BB * SS;          // 4096
constexpr int WHALF = 256;             // window // 2
constexpr int NGLOB = 64;
constexpr float NEGBIG = -1e10f;

// Workspace layout (bytes)
constexpr size_t SZ_X1    = (size_t)NTOK * DDIM * 2;
constexpr size_t SZ_WQKVT = (size_t)1536 * DDIM * 2;
constexpr size_t SZ_WOT   = (size_t)DDIM * DDIM * 2;
constexpr size_t SZ_W1T   = (size_t)MLPD * DDIM * 2;
constexpr size_t SZ_W2T   = (size_t)DDIM * MLPD * 2;
constexpr size_t SZ_HEAD  = (size_t)BB * NHEAD * SS * HDIM * 2;
constexpr size_t SZ_QKV   = 3 * SZ_HEAD;
constexpr size_t SZ_CTX   = (size_t)NTOK * DDIM * 2;
constexpr size_t SZ_XRES  = (size_t)NTOK * DDIM * 4;
constexpr size_t SZ_Y1    = (size_t)NTOK * DDIM * 2;
constexpr size_t SZ_H1    = (size_t)NTOK * MLPD * 2;

constexpr size_t OFF_X1    = 0;
constexpr size_t OFF_WQKVT = OFF_X1 + SZ_X1;
constexpr size_t OFF_WOT   = OFF_WQKVT + SZ_WQKVT;
constexpr size_t OFF_W1T   = OFF_WOT + SZ_WOT;
constexpr size_t OFF_W2T   = OFF_W1T + SZ_W1T;
constexpr size_t OFF_QKV   = OFF_W2T + SZ_W2T;
constexpr size_t OFF_CTX   = OFF_QKV + SZ_QKV;
constexpr size_t OFF_XRES  = OFF_CTX + SZ_CTX;
constexpr size_t OFF_Y1    = OFF_XRES + SZ_XRES;
constexpr size_t OFF_H1    = OFF_Y1 + SZ_Y1;
constexpr size_t OFF_GACC  = OFF_H1 + SZ_H1;                        // [64][64][64] f32
constexpr size_t OFF_GL    = OFF_GACC + (size_t)64 * 64 * 64 * 4;   // [64][64] f32

// ---------------------------------------------------------------------------
// Prep kernel: blocks 0..767 = weight transpose+cast; 768..1791 = LN1.
// ---------------------------------------------------------------------------
struct TcEnt { const float* src; bf16* dst; int K, N, tiles_x, start; float scale; };
struct PrepArgs {
  TcEnt e[6];
  const float* x; const float* ln_s; const float* ln_b; bf16* ln_out;
};

__global__ void prep_kernel(PrepArgs a) {
  __shared__ __align__(16) bf16 tile[64][65];
  int bid = blockIdx.x;
  int t = threadIdx.x;
  if (bid < 768) {
    int wi = 5;
#pragma unroll
    for (int i = 4; i >= 0; --i)
      if (bid < a.e[i + 1].start) wi = i;
    const TcEnt& E = a.e[wi];
    int local = bid - E.start;
    int bx = local % E.tiles_x, by = local / E.tiles_x;
    int k0 = by * 64, n0 = bx * 64;
    for (int it = 0; it < 16; ++it) {
      int idx = it * 256 + t;
      int r = idx >> 6, c = idx & 63;
      float v = E.src[(size_t)(k0 + r) * E.N + n0 + c] * E.scale;
      tile[c][r] = __float2bfloat16(v);
    }
    __syncthreads();
    for (int it = 0; it < 16; ++it) {
      int idx = it * 256 + t;
      int r = idx >> 6, c = idx & 63;
      E.dst[(size_t)(n0 + r) * E.K + k0 + c] = tile[r][c];
    }
  } else {
    int wv = t >> 6;
    int lane = t & 63;
    int row = (bid - 768) * 4 + wv;
    const float* xr = a.x + (size_t)row * DDIM + lane * 8;
    float4 v0 = *(const float4*)(xr);
    float4 v1 = *(const float4*)(xr + 4);
    float vv[8] = {v0.x, v0.y, v0.z, v0.w, v1.x, v1.y, v1.z, v1.w};
    float s = 0.f;
    for (int i = 0; i < 8; ++i) s += vv[i];
    for (int m = 1; m < 64; m <<= 1) s += __shfl_xor(s, m, 64);
    float mean = s * (1.0f / DDIM);
    float vs = 0.f;
    for (int i = 0; i < 8; ++i) { float d = vv[i] - mean; vs += d * d; }
    for (int m = 1; m < 64; m <<= 1) vs += __shfl_xor(vs, m, 64);
    float rstd = rsqrtf(vs * (1.0f / DDIM) + 1e-6f);
    __align__(16) bf16 ov[8];
    int c0 = lane * 8;
    for (int i = 0; i < 8; ++i) {
      float y = (vv[i] - mean) * rstd * a.ln_s[c0 + i] + a.ln_b[c0 + i];
      ov[i] = __float2bfloat16(y);
    }
    *(uint4*)(&a.ln_out[(size_t)row * DDIM + c0]) = *(const uint4*)ov;
  }
}

// ---------------------------------------------------------------------------
// LayerNorm (fp32 in) -> bf16 out. One wave per 512-el row.
// ---------------------------------------------------------------------------
__global__ void ln_kernel(const float* __restrict__ x, const float* __restrict__ sc,
                          const float* __restrict__ bi, bf16* __restrict__ out) {
  int wv = threadIdx.x >> 6;
  int lane = threadIdx.x & 63;
  int row = blockIdx.x * 4 + wv;
  const float* xr = x + (size_t)row * DDIM + lane * 8;
  float4 v0 = *(const float4*)(xr);
  float4 v1 = *(const float4*)(xr + 4);
  float vv[8] = {v0.x, v0.y, v0.z, v0.w, v1.x, v1.y, v1.z, v1.w};
  float s = 0.f;
  for (int i = 0; i < 8; ++i) s += vv[i];
  for (int m = 1; m < 64; m <<= 1) s += __shfl_xor(s, m, 64);
  float mean = s * (1.0f / DDIM);
  float vs = 0.f;
  for (int i = 0; i < 8; ++i) { float d = vv[i] - mean; vs += d * d; }
  for (int m = 1; m < 64; m <<= 1) vs += __shfl_xor(vs, m, 64);
  float rstd = rsqrtf(vs * (1.0f / DDIM) + 1e-6f);
  __align__(16) bf16 ov[8];
  int c0 = lane * 8;
  for (int i = 0; i < 8; ++i) {
    float y = (vv[i] - mean) * rstd * sc[c0 + i] + bi[c0 + i];
    ov[i] = __float2bfloat16(y);
  }
  *(uint4*)(&out[(size_t)row * DDIM + c0]) = *(const uint4*)ov;
}

// ---------------------------------------------------------------------------
// GEMM: double-buffered LDS, global_load_lds staging, 2-phase pipeline.
// NP = K-panels per epoch (epoch K-step = NP*64). Round-13 configuration.
// ---------------------------------------------------------------------------
template <int BM, int BN, int NP, int EPI>
__global__ __launch_bounds__(256,
    ((2 * NP * (BM + BN) * 128 / 1024) <= 32) ? 4 :
    (((2 * NP * (BM + BN) * 128 / 1024) <= 48) ? 3 : 2))
void gemm_kernel(const bf16* __restrict__ A, const bf16* __restrict__ BT,
                 int M, int N, int K, int gx,
                 const float* __restrict__ ep_add, const float* __restrict__ ep_bias,
                 void* __restrict__ out0) {
  constexpr int AM = BM / 32;
  constexpr int AN = BN / 32;
  constexpr int CA4 = (BM / 8) / 4;
  constexpr int CB4 = (BN / 8) / 4;
  __shared__ __align__(16) bf16 As[2][NP][BM][64];
  __shared__ __align__(16) bf16 Bs[2][NP][BN][64];
  int t = threadIdx.x;
  int wv = t >> 6, lane = t & 63;
  int wr = wv >> 1, wc = wv & 1;
  int g = lane >> 4, lr = lane & 15;
  int sub_r = lane >> 3, sub_s = lane & 7;
  int nwg = gridDim.x;
  int bid = blockIdx.x;
  int swz = (bid & 7) * (nwg >> 3) + (bid >> 3);
  int m0 = (swz / gx) * BM;
  int n0 = (swz % gx) * BN;
  lchar_t asA = (lchar_t)&As[0][0][0][0];
  lchar_t asB = (lchar_t)&Bs[0][0][0][0];

  auto stage = [&](int kt, int bb) {
    int k0 = kt * (64 * NP);
#pragma unroll
    for (int p = 0; p < NP; ++p) {
#pragma unroll
      for (int i = 0; i < CA4; ++i) {
        int c = wv + 4 * i;
        int row = c * 8 + sub_r;
        int cb = sub_s ^ sub_r;
        __builtin_amdgcn_global_load_lds(
            (gptr_t)&A[(size_t)(m0 + row) * K + k0 + p * 64 + cb * 8],
            (lptr_t)(asA + bb * (NP * BM * 128) + p * (BM * 128) + c * 1024), 16, 0, 0);
      }
#pragma unroll
      for (int i = 0; i < CB4; ++i) {
        int c = wv + 4 * i;
        int row = c * 8 + sub_r;
        int cb = sub_s ^ sub_r;
        __builtin_amdgcn_global_load_lds(
            (gptr_t)&BT[(size_t)(n0 + row) * K + k0 + p * 64 + cb * 8],
            (lptr_t)(asB + bb * (NP * BN * 128) + p * (BN * 128) + c * 1024), 16, 0, 0);
      }
    }
  };

  f32x4 acc[AM][AN] = {};
  int NT = K / (64 * NP);
  stage(0, 0);
  asm volatile("s_waitcnt vmcnt(0)" ::: "memory");
  __builtin_amdgcn_s_barrier();
  __builtin_amdgcn_sched_barrier(0);
  for (int kt = 0; kt < NT; ++kt) {
    int bb = kt & 1;
    if (kt + 1 < NT) stage(kt + 1, bb ^ 1);
    const char* Ab = (const char*)&As[0][0][0][0] + bb * (NP * BM * 128);
    const char* Bb = (const char*)&Bs[0][0][0][0] + bb * (NP * BN * 128);
#pragma unroll
    for (int p = 0; p < NP; ++p) {
#pragma unroll
      for (int h = 0; h < 2; ++h) {
        bf16x8 af[AM], bfr[AN];
#pragma unroll
        for (int i = 0; i < AM; ++i) {
          int row = wr * (BM / 2) + i * 16 + lr;
          int sl = (h * 4 + g) ^ (row & 7);
          af[i] = *(const bf16x8*)(Ab + p * (BM * 128) + row * 128 + sl * 16);
        }
#pragma unroll
        for (int j = 0; j < AN; ++j) {
          int row = wc * (BN / 2) + j * 16 + lr;
          int sl = (h * 4 + g) ^ (row & 7);
          bfr[j] = *(const bf16x8*)(Bb + p * (BN * 128) + row * 128 + sl * 16);
        }
#pragma unroll
        for (int i = 0; i < AM; ++i)
#pragma unroll
          for (int j = 0; j < AN; ++j)
            acc[i][j] = __builtin_amdgcn_mfma_f32_16x16x32_bf16(af[i], bfr[j], acc[i][j], 0, 0, 0);
      }
    }
    asm volatile("s_waitcnt vmcnt(0)" ::: "memory");
    __builtin_amdgcn_s_barrier();
    __builtin_amdgcn_sched_barrier(0);
  }
#pragma unroll
  for (int i = 0; i < AM; ++i)
#pragma unroll
    for (int j = 0; j < AN; ++j)
#pragma unroll
      for (int r = 0; r < 4; ++r) {
        int m = m0 + wr * (BM / 2) + i * 16 + g * 4 + r;
        int n = n0 + wc * (BN / 2) + j * 16 + lr;
        float val = acc[i][j][r];
        if constexpr (EPI == 0) {
          bf16* qkv = (bf16*)out0;
          int which = n >> 9;
          int hh = (n >> 6) & 7;
          int hd = n & 63;
          int b = m >> 11, sTok = m & 2047;
          size_t off;
          if (which == 2) {
            off = (size_t)2 * (BB * NHEAD * SS * HDIM) +
                  ((size_t)(b * NHEAD + hh) * HDIM + hd) * SS + sTok;
          } else {
            off = (size_t)which * (BB * NHEAD * SS * HDIM) +
                  ((size_t)(b * NHEAD + hh) * SS + sTok) * HDIM + hd;
          }
          qkv[off] = __float2bfloat16(val);
        } else if constexpr (EPI == 1) {
          ((float*)out0)[(size_t)m * N + n] = val + ep_add[(size_t)m * N + n];
        } else if constexpr (EPI == 2) {
          float xb = val + ep_bias[n];
          float u = 1.5957691216057308f * (xb + 0.044715f * xb * xb * xb);
          float ge = xb / (1.0f + __expf(-u));
          ((bf16*)out0)[(size_t)m * N + n] = __float2bfloat16(ge);
        } else {
          ((float*)out0)[(size_t)m * N + n] = val + ep_bias[n] + ep_add[(size_t)m * N + n];
        }
      }
}

// ---------------------------------------------------------------------------
// Block-sparse flash attention v8b (round-13 version: no setprio).
// 64 q-rows per block, 4 waves. K/V 64-key tiles staged via global_load_lds,
// double-buffered 2-phase. Fixed softmax reference m == 0.
// ---------------------------------------------------------------------------
constexpr int NBANDQ = (SS - NGLOB) / 64;      // 31 band q-tiles per head
constexpr int NBAND8 = 16 * NBANDQ;            // 496
constexpr int NGSPL8 = 16 * 4;                 // 64 (1 q-tile x 4 kv-splits)
constexpr int NWG8   = NBAND8 + NGSPL8;        // 560 (divisible by 8)

__global__ __launch_bounds__(256, 3)
void attn_kernel(const bf16* __restrict__ Qb, const bf16* __restrict__ Kb,
                 const bf16* __restrict__ VTb, bf16* __restrict__ ctx,
                 float* __restrict__ gacc, float* __restrict__ gl) {
  __shared__ __align__(16) bf16 Ks[2][64][64];   // [buf][key][d]   8KB each
  __shared__ __align__(16) bf16 Vs[2][64][64];   // [buf][d][key]   8KB each
  __shared__ __align__(16) bf16 Plds[4][16][72];
  int t = threadIdx.x;
  int w = t >> 6, lane = t & 63;
  int g = lane >> 4, lr = lane & 15;
  int sub_r = lane >> 3, sub_s = lane & 7;
  int bid = blockIdx.x;
  int swz = (bid & 7) * (NWG8 / 8) + (bid >> 3);

  bool isBand = swz < NBAND8;
  int bh, qq0, k0 = 0, sp = 0;
  if (isBand) {
    bh = swz / NBANDQ;
    qq0 = NGLOB + (swz % NBANDQ) * 64;           // 64..1984
  } else {
    int gidx = swz - NBAND8;
    bh = gidx >> 2;
    sp = gidx & 3;
    qq0 = 0;                                     // global rows 0..63
    k0 = sp * (SS / 4);
  }
  int b = bh >> 3, h = bh & 7;
  const bf16* Qh = Qb + (size_t)bh * SS * HDIM;
  const bf16* Kh = Kb + (size_t)bh * SS * HDIM;
  const bf16* VTh = VTb + (size_t)bh * HDIM * SS;
  int qq0w = qq0 + w * 16;

  bf16x8 aq0 = *(const bf16x8*)&Qh[(size_t)(qq0w + lr) * HDIM + g * 8];
  bf16x8 aq1 = *(const bf16x8*)&Qh[(size_t)(qq0w + lr) * HDIM + 32 + g * 8];

  lchar_t ksB = (lchar_t)&Ks[0][0][0];
  lchar_t vsB = (lchar_t)&Vs[0][0][0];
  int cb = sub_s ^ sub_r;

  auto stageKV = [&](int kb, int bb) {
#pragma unroll
    for (int i = 0; i < 2; ++i) {
      int c = w + 4 * i;
      int row = c * 8 + sub_r;
      __builtin_amdgcn_global_load_lds(
          (gptr_t)&Kh[(size_t)(kb + row) * HDIM + cb * 8],
          (lptr_t)(ksB + bb * 8192 + c * 1024), 16, 0, 0);
      __builtin_amdgcn_global_load_lds(
          (gptr_t)&VTh[(size_t)row * SS + kb + cb * 8],
          (lptr_t)(vsB + bb * 8192 + c * 1024), 16, 0, 0);
    }
  };

  float lsum[4] = {0.f, 0.f, 0.f, 0.f};
  f32x4 accO[4] = {};
  const char* ksR = (const char*)&Ks[0][0][0];
  const char* vsR = (const char*)&Vs[0][0][0];

  auto computeT = [&](int kb, int bb, bool domask) {
    const char* Kb_ = ksR + bb * 8192;
    const char* Vb_ = vsR + bb * 8192;
    f32x4 s[4];
#pragma unroll
    for (int sub = 0; sub < 4; ++sub) {
      int row = sub * 16 + lr;
      int sl0 = g ^ (row & 7);
      int sl1 = (4 + g) ^ (row & 7);
      bf16x8 ka = *(const bf16x8*)(Kb_ + row * 128 + sl0 * 16);
      bf16x8 kc = *(const bf16x8*)(Kb_ + row * 128 + sl1 * 16);
      f32x4 z = {};
      z = __builtin_amdgcn_mfma_f32_16x16x32_bf16(aq0, ka, z, 0, 0, 0);
      z = __builtin_amdgcn_mfma_f32_16x16x32_bf16(aq1, kc, z, 0, 0, 0);
      s[sub] = z;
    }
    if (domask) {
#pragma unroll
      for (int sub = 0; sub < 4; ++sub)
#pragma unroll
        for (int r = 0; r < 4; ++r) {
          int i = qq0w + g * 4 + r;
          int d = i - (kb + sub * 16 + lr);
          bool ok = (unsigned)(d + WHALF) <= 2u * WHALF;
          s[sub][r] = ok ? s[sub][r] : NEGBIG;
        }
    }
    float p[4][4];
#pragma unroll
    for (int sub = 0; sub < 4; ++sub)
#pragma unroll
      for (int r = 0; r < 4; ++r) p[sub][r] = __expf(s[sub][r]);
#pragma unroll
    for (int r = 0; r < 4; ++r)
      lsum[r] += (p[0][r] + p[1][r]) + (p[2][r] + p[3][r]);
#pragma unroll
    for (int sub = 0; sub < 4; ++sub)
#pragma unroll
      for (int r = 0; r < 4; ++r)
        Plds[w][g * 4 + r][sub * 16 + lr] = __float2bfloat16(p[sub][r]);
    asm volatile("s_waitcnt lgkmcnt(0)" ::: "memory");
    __builtin_amdgcn_sched_barrier(0);
    bf16x8 paLo = *(const bf16x8*)&Plds[w][lr][g * 8];
    bf16x8 paHi = *(const bf16x8*)&Plds[w][lr][32 + g * 8];
#pragma unroll
    for (int dc = 0; dc < 4; ++dc) {
      int row = dc * 16 + lr;
      int slLo = g ^ (row & 7);
      int slHi = (4 + g) ^ (row & 7);
      bf16x8 vfLo = *(const bf16x8*)(Vb_ + row * 128 + slLo * 16);
      bf16x8 vfHi = *(const bf16x8*)(Vb_ + row * 128 + slHi * 16);
      accO[dc] = __builtin_amdgcn_mfma_f32_16x16x32_bf16(paLo, vfLo, accO[dc], 0, 0, 0);
      accO[dc] = __builtin_amdgcn_mfma_f32_16x16x32_bf16(paHi, vfHi, accO[dc], 0, 0, 0);
    }
  };

  int bs = 0, nt;
  if (isBand) {
    int blo = qq0 - WHALF;
    bs = (blo < NGLOB) ? NGLOB : (blo & ~63);
    int be = qq0 + 64 + WHALF;
    if (be > SS) be = SS;
    nt = 1 + ((be - bs + 63) >> 6);
  } else {
    nt = (SS / 4) / 64;                          // 8
  }
  auto kb_of = [&](int i) {
    if (isBand) return (i == 0) ? 0 : bs + (i - 1) * 64;
    return k0 + i * 64;
  };

  stageKV(kb_of(0), 0);
  asm volatile("s_waitcnt vmcnt(0)" ::: "memory");
  __builtin_amdgcn_s_barrier();
  __builtin_amdgcn_sched_barrier(0);
  for (int i = 0; i < nt; ++i) {
    int bb = i & 1;
    if (i + 1 < nt) stageKV(kb_of(i + 1), bb ^ 1);
    int kb = kb_of(i);
    bool domask = isBand && (i > 0) &&
                  ((kb < qq0w - 241) || (kb + 63 > qq0w + WHALF));
    computeT(kb, bb, domask);
    asm volatile("s_waitcnt vmcnt(0)" ::: "memory");
    __builtin_amdgcn_s_barrier();
    __builtin_amdgcn_sched_barrier(0);
  }

#pragma unroll
  for (int m = 1; m < 16; m <<= 1)
#pragma unroll
    for (int r = 0; r < 4; ++r) lsum[r] += __shfl_xor(lsum[r], m, 64);

  if (isBand) {
#pragma unroll
    for (int r = 0; r < 4; ++r) {
      float rL = 1.0f / lsum[r];
      int m = b * SS + qq0w + g * 4 + r;
#pragma unroll
      for (int dc = 0; dc < 4; ++dc) {
        int col = h * HDIM + dc * 16 + lr;
        ctx[(size_t)m * DDIM + col] = __float2bfloat16(accO[dc][r] * rL);
      }
    }
  } else {
    int grp = bh * 4 + sp;
#pragma unroll
    for (int r = 0; r < 4; ++r) {
      int rowi = w * 16 + g * 4 + r;
#pragma unroll
      for (int dc = 0; dc < 4; ++dc)
        gacc[((size_t)grp * 64 + rowi) * 64 + dc * 16 + lr] = accO[dc][r];
      if (lr == 0) gl[grp * 64 + rowi] = lsum[r];
    }
  }
}

// Merge the 4 KV-splits of each head's global q-rows (plain sums, shared m==0).
// 64 blocks: (bh, quarter) — each handles 16 rows (4x more parallel than r13).
__global__ __launch_bounds__(64, 4)
void attn_combine_kernel(const float* __restrict__ gacc, const float* __restrict__ gl,
                         bf16* __restrict__ ctx) {
  int bh = blockIdx.x >> 2;       // 0..15
  int rq = blockIdx.x & 3;        // row quarter
  int b = bh >> 3, h = bh & 7;
  int c = threadIdx.x;
  for (int rr = 0; rr < 16; ++rr) {
    int r = rq * 16 + rr;
    float L = 0.f, val = 0.f;
    for (int s2 = 0; s2 < 4; ++s2) {
      L += gl[(bh * 4 + s2) * 64 + r];
      val += gacc[((size_t)(bh * 4 + s2) * 64 + r) * 64 + c];
    }
    ctx[(size_t)(b * SS + r) * DDIM + h * HDIM + c] = __float2bfloat16(val / L);
  }
}

// ---------------------------------------------------------------------------
extern "C" void kernel_launch(void* const* d_in, const int* in_sizes, int n_in,
                              void* d_out, int out_size, void* d_ws, size_t ws_size,
                              hipStream_t stream) {
  const float* inputs = (const float*)d_in[0];
  const float* ln1_s = (const float*)d_in[2];
  const float* ln1_b = (const float*)d_in[3];
  const float* wq = (const float*)d_in[4];
  const float* wk = (const float*)d_in[5];
  const float* wv = (const float*)d_in[6];
  const float* wo = (const float*)d_in[7];
  const float* ln2_s = (const float*)d_in[8];
  const float* ln2_b = (const float*)d_in[9];
  const float* w1 = (const float*)d_in[10];
  const float* b1 = (const float*)d_in[11];
  const float* w2 = (const float*)d_in[12];
  const float* b2 = (const float*)d_in[13];

  char* ws = (char*)d_ws;
  bf16* x1    = (bf16*)(ws + OFF_X1);
  bf16* wqkvT = (bf16*)(ws + OFF_WQKVT);
  bf16* woT   = (bf16*)(ws + OFF_WOT);
  bf16* w1T   = (bf16*)(ws + OFF_W1T);
  bf16* w2T   = (bf16*)(ws + OFF_W2T);
  bf16* qkv   = (bf16*)(ws + OFF_QKV);
  bf16* ctx   = (bf16*)(ws + OFF_CTX);
  float* xres = (float*)(ws + OFF_XRES);
  bf16* y1    = (bf16*)(ws + OFF_Y1);
  bf16* h1    = (bf16*)(ws + OFF_H1);
  float* gacc = (float*)(ws + OFF_GACC);
  float* gl   = (float*)(ws + OFF_GL);
  size_t headsz = (size_t)BB * NHEAD * SS * HDIM;

  // Prep: 6 weight transposes (fold 1/8 into wq) + LN1 in one launch
  PrepArgs pa;
  pa.e[0] = {wq, wqkvT,                       512, 512,  8,   0, 0.125f};
  pa.e[1] = {wk, wqkvT + (size_t)512 * 512,   512, 512,  8,  64, 1.f};
  pa.e[2] = {wv, wqkvT + (size_t)1024 * 512,  512, 512,  8, 128, 1.f};
  pa.e[3] = {wo, woT,                         512, 512,  8, 192, 1.f};
  pa.e[4] = {w1, w1T,                         512, 2048, 32, 256, 1.f};
  pa.e[5] = {w2, w2T,                         2048, 512, 8, 512, 1.f};
  pa.x = inputs; pa.ln_s = ln1_s; pa.ln_b = ln1_b; pa.ln_out = x1;
  prep_kernel<<<768 + NTOK / 4, 256, 0, stream>>>(pa);

  // QKV projection (V written transposed): 64x128, BK=64 -> 768 wgs, 3/CU exact
  gemm_kernel<64, 128, 1, 0><<<12 * 64, 256, 0, stream>>>(x1, wqkvT, NTOK, 1536, 512, 12, nullptr, nullptr, qkv);
  // Attention: 64-row q-tiles, 4 waves, 560 blocks, 3 blocks/CU
  attn_kernel<<<NWG8, 256, 0, stream>>>(qkv, qkv + headsz, qkv + 2 * headsz, ctx, gacc, gl);
  attn_combine_kernel<<<64, 64, 0, stream>>>(gacc, gl, ctx);
  // Output projection + residual: 64x64, BK=128 -> 4 epochs
  gemm_kernel<64, 64, 2, 1><<<8 * 64, 256, 0, stream>>>(ctx, woT, NTOK, 512, 512, 8, inputs, nullptr, xres);
  // LN2
  ln_kernel<<<NTOK / 4, 256, 0, stream>>>(xres, ln2_s, ln2_b, y1);
  // MLP up: 128x128, BK=64 -> 512 wgs, 2/CU exact
  gemm_kernel<128, 128, 1, 2><<<16 * 32, 256, 0, stream>>>(y1, w1T, NTOK, 2048, 512, 16, nullptr, b1, h1);
  // MLP down: 64x64, BK=128 -> 16 epochs, 512 wgs, 2/CU exact
  gemm_kernel<64, 64, 2, 3><<<8 * 64, 256, 0, stream>>>(h1, w2T, NTOK, 512, 2048, 8, xres, b2, (float*)d_out);
}